// Round 2
// baseline (2994.657 us; speedup 1.0000x reference)
//
#include <hip/hip_runtime.h>

// Single-pass peak detection + ordered stream compaction via decoupled
// lookback (rocPRIM/CUB style). Heatmap (8,16,512,512) fp32.
//
// Key facts (measured R1): counts[b] ~= 466944 > max_peaks=262144, so every
// output row is written by the compaction -> no d_out memset needed.

namespace {
constexpr int kB = 8;
constexpr int kC = 16;
constexpr int kH = 512;
constexpr int kW = 512;
constexpr int kNPB = kC * kH * kW;                  // 4,194,304 px / batch
constexpr int kMaxPeaks = 262144;
constexpr int kTPB = 256;
constexpr int kPixPerBlock = kTPB * 4;              // 1024 = 2 rows
constexpr int kNBlkPerBatch = kNPB / kPixPerBlock;  // 4096 (chain length)
constexpr int kNBlocks = kB * kNBlkPerBatch;        // 32768
constexpr long long kPeaksElems = (long long)kB * kMaxPeaks * 3;

constexpr unsigned long long FLAG_AGG = 1ull << 62;
constexpr unsigned long long FLAG_INC = 2ull << 62;
constexpr unsigned long long FLAG_MASK = 3ull << 62;
constexpr unsigned long long VAL_MASK = (1ull << 62) - 1;
}

// Load 6 floats (halo-1 .. halo+4) of row yy, or -FLT_MAX outside the image.
__device__ __forceinline__ void load_row6(const float* __restrict__ img,
                                          int yy, int x0, float r[6]) {
  const float NEG = -3.402823466e38f;
  if (yy >= 0 && yy < kH) {
    const float* p = img + yy * kW + x0;
    float4 c4 = *reinterpret_cast<const float4*>(p);  // x0 % 4 == 0
    r[1] = c4.x; r[2] = c4.y; r[3] = c4.z; r[4] = c4.w;
    r[0] = (x0 > 0) ? p[-1] : NEG;
    r[5] = (x0 + 4 < kW) ? p[4] : NEG;
  } else {
#pragma unroll
    for (int i = 0; i < 6; ++i) r[i] = NEG;
  }
}

__global__ void __launch_bounds__(kTPB)
peak_fused_kernel(const float* __restrict__ hm,
                  unsigned long long* __restrict__ ws,
                  float* __restrict__ out) {
  __shared__ int s_vid;
  __shared__ int s_excl;
  __shared__ int s_wsum[kTPB / 64];

  unsigned long long* ticket = ws;       // ws[0]
  unsigned long long* desc = ws + 8;     // 64B-offset descriptor array

  const int t = threadIdx.x;

  // Virtual block id in dispatch-start order: lookback then only ever waits
  // on blocks that have already started -> no deadlock regardless of HW
  // scheduling order.
  if (t == 0) s_vid = (int)atomicAdd(ticket, 1ull);
  __syncthreads();
  const int vid = s_vid;

  const int b = vid >> 12;           // / 4096
  const int chain = vid & 4095;      // position in this batch's chain
  const int dbase = vid - chain;     // descriptor index of chain element 0
  const int local = chain * kPixPerBlock + t * 4;  // flat px within batch
  const int c = local >> 18;         // / (512*512)
  const int y = (local >> 9) & (kH - 1);
  const int x0 = local & (kW - 1);   // multiple of 4
  const float* img = hm + (long long)b * kNPB + c * (kH * kW);

  // ---- 3x3 local-max flags for 4 pixels (10 max3 ops) ----
  float r0[6], r1[6], r2[6];
  load_row6(img, y - 1, x0, r0);
  load_row6(img, y,     x0, r1);
  load_row6(img, y + 1, x0, r2);
  float colmax[6];
#pragma unroll
  for (int i = 0; i < 6; ++i)
    colmax[i] = fmaxf(fmaxf(r0[i], r1[i]), r2[i]);   // -> v_max3_f32
  int f[4];
  int cnt = 0;
#pragma unroll
  for (int i = 0; i < 4; ++i) {
    float m = fmaxf(fmaxf(colmax[i], colmax[i + 1]), colmax[i + 2]);
    f[i] = ((r1[i + 1] == m) && (r1[i + 1] > 0.0f)) ? 1 : 0;
    cnt += f[i];
  }

  // ---- block-local exclusive scan (thread order == flat-index order) ----
  const int lane = t & 63, wv = t >> 6;
  int incl = cnt;
#pragma unroll
  for (int d = 1; d < 64; d <<= 1) {
    int u = __shfl_up(incl, d, 64);
    if (lane >= d) incl += u;
  }
  if (lane == 63) s_wsum[wv] = incl;
  __syncthreads();
  int wbase = 0;
  for (int i = 0; i < wv; ++i) wbase += s_wsum[i];
  const int A = s_wsum[0] + s_wsum[1] + s_wsum[2] + s_wsum[3];  // block aggregate
  const int lexcl = wbase + incl - cnt;  // this thread's local exclusive rank

  // ---- publish aggregate, then decoupled lookback (wave 0) ----
  if (t == 0) {
    unsigned long long d0 =
        (chain == 0 ? FLAG_INC : FLAG_AGG) | (unsigned long long)A;
    __hip_atomic_store(&desc[vid], d0, __ATOMIC_RELEASE,
                       __HIP_MEMORY_SCOPE_AGENT);
    if (chain == 0) s_excl = 0;
  }
  if (chain != 0 && wv == 0) {
    int excl = 0;
    int j = chain - 1;  // chain position inspected by lane 0
    for (;;) {
      const int idx = j - lane;
      unsigned long long d =
          (idx >= 0) ? __hip_atomic_load(&desc[dbase + idx], __ATOMIC_ACQUIRE,
                                         __HIP_MEMORY_SCOPE_AGENT)
                     : FLAG_INC;  // virtual INC(0) before chain start
      const unsigned long long fl = d & FLAG_MASK;
      const unsigned long long mask_inc = __ballot(fl == FLAG_INC);
      const unsigned long long mask_inv = __ballot(fl == 0);
      if (mask_inc != 0) {
        const int first = __ffsll((long long)mask_inc) - 1;  // nearest INC
        const unsigned long long nearer = (1ull << first) - 1ull;
        if ((mask_inv & nearer) == 0) {  // all nearer lanes have valid AGG
          int contrib = (lane <= first) ? (int)(d & VAL_MASK) : 0;
#pragma unroll
          for (int s = 32; s >= 1; s >>= 1) contrib += __shfl_down(contrib, s, 64);
          excl += __shfl(contrib, 0, 64);
          break;
        }
      } else if (mask_inv == 0) {  // full window of AGGs: keep walking back
        int contrib = (int)(d & VAL_MASK);
#pragma unroll
        for (int s = 32; s >= 1; s >>= 1) contrib += __shfl_down(contrib, s, 64);
        excl += __shfl(contrib, 0, 64);
        j -= 64;
        continue;
      }
      __builtin_amdgcn_s_sleep(1);  // window not ready; back off and retry
    }
    if (lane == 0) {
      __hip_atomic_store(&desc[vid],
                         FLAG_INC | (unsigned long long)(excl + A),
                         __ATOMIC_RELEASE, __HIP_MEMORY_SCOPE_AGENT);
      s_excl = excl;
    }
  }
  __syncthreads();
  const int excl = s_excl;

  // ---- outputs ----
  if (chain == kNBlkPerBatch - 1 && t == 0)
    out[kPeaksElems + b] = (float)(excl + A);  // counts[b] (full, uncapped)

  int rank = excl + lexcl;
  if (rank < kMaxPeaks) {  // blocks entirely past the cap skip the store loop
    float* pb = out + (long long)b * kMaxPeaks * 3;
#pragma unroll
    for (int i = 0; i < 4; ++i) {
      if (f[i] && rank < kMaxPeaks) {
        float* o = pb + (long long)rank * 3;
        o[0] = (float)(x0 + i);
        o[1] = (float)y;
        o[2] = r1[i + 1];
      }
      rank += f[i];
    }
  }
}

extern "C" void kernel_launch(void* const* d_in, const int* in_sizes, int n_in,
                              void* d_out, int out_size, void* d_ws, size_t ws_size,
                              hipStream_t stream) {
  const float* hm = (const float*)d_in[0];
  float* out = (float*)d_out;

  // ws layout: [0] ticket, [8..8+32768) descriptors (u64 each).
  hipMemsetAsync(d_ws, 0, (size_t)(kNBlocks + 8) * sizeof(unsigned long long),
                 stream);
  peak_fused_kernel<<<kNBlocks, kTPB, 0, stream>>>(
      hm, (unsigned long long*)d_ws, out);
}

// Round 3
// 234.003 us; speedup vs baseline: 12.7975x; 12.7975x over previous
//
#include <hip/hip_runtime.h>

// Two-pass peak detection + ordered compaction, (8,16,512,512) fp32.
// R2 established: single-pass decoupled lookback is coherence-latency-bound on
// multi-XCD gfx950 (2.9ms). R1 two-pass worked (277us total incl ~120us harness
// floor). This version cuts traffic: pass1 emits ballot bitmasks so pass3 never
// recomputes flags, reads only center rows for conf, and skips blocks fully
// past the max_peaks cap (counts ~467K > 262144, ~44% of blocks skip).

namespace {
constexpr int kB = 8;
constexpr int kC = 16;
constexpr int kH = 512;
constexpr int kW = 512;
constexpr int kNPB = kC * kH * kW;                  // 4,194,304 px / batch
constexpr int kMaxPeaks = 262144;
constexpr int kTPB = 256;
constexpr int kPixPerBlock = kTPB * 4;              // 1024 = 2 rows
constexpr int kNBlkPerBatch = kNPB / kPixPerBlock;  // 4096
constexpr int kNBlocks = kB * kNBlkPerBatch;        // 32768
constexpr long long kPeaksElems = (long long)kB * kMaxPeaks * 3;
constexpr float kNeg = -3.402823466e38f;
}

__device__ __forceinline__ float fmax3(float a, float b, float c) {
  return fmaxf(fmaxf(a, b), c);  // -> v_max3_f32
}

// Decode block/thread -> (batch, channel, y, x0). Thread order == flat order.
__device__ __forceinline__ void decode(int blk, int t, int& b, int& c, int& y,
                                       int& x0) {
  b = blk >> 12;
  int local = (blk & 4095) * kPixPerBlock + t * 4;
  c = local >> 18;
  y = (local >> 9) & (kH - 1);
  x0 = local & (kW - 1);  // multiple of 4; within a wave all lanes share a row
}

// Pass 1: flags via shuffle-halo, emit per-wave ballot words + block count.
__global__ void __launch_bounds__(kTPB)
peak_count_kernel(const float* __restrict__ hm,
                  unsigned long long* __restrict__ bm,
                  int* __restrict__ blk_cnt) {
  const int t = threadIdx.x, lane = t & 63, wv = t >> 6;
  int b, c, y, x0;
  decode(blockIdx.x, t, b, c, y, x0);
  const float* img = hm + (long long)b * kNPB + c * (kH * kW);

  // rows y-1..y+1: own float4 + halos from neighbor lanes.
  float a[3][6];
#pragma unroll
  for (int j = 0; j < 3; ++j) {
    const int yy = y + j - 1;
    const bool ok = (yy >= 0) & (yy < kH);
    const float* p = img + yy * kW + x0;
    float4 r;
    if (ok) r = *reinterpret_cast<const float4*>(p);
    else    r = make_float4(kNeg, kNeg, kNeg, kNeg);
    float L = __shfl_up(r.w, 1, 64);    // left halo from lane-1
    float R = __shfl_down(r.x, 1, 64);  // right halo from lane+1
    // wave-edge + image-edge fixups (lanes 0 and 63 only)
    if (lane == 0)  L = (ok && x0 > 0)        ? p[-1] : kNeg;
    if (lane == 63) R = (ok && x0 + 4 < kW)   ? p[4]  : kNeg;
    a[j][0] = L; a[j][1] = r.x; a[j][2] = r.y; a[j][3] = r.z; a[j][4] = r.w;
    a[j][5] = R;
  }

  float cm[6];
#pragma unroll
  for (int i = 0; i < 6; ++i) cm[i] = fmax3(a[0][i], a[1][i], a[2][i]);

  unsigned long long w[4];
#pragma unroll
  for (int i = 0; i < 4; ++i) {
    const float v = a[1][i + 1];
    const float m = fmax3(cm[i], cm[i + 1], cm[i + 2]);
    w[i] = __ballot((v == m) && (v > 0.0f));
  }

  // store 4 ballot words (wave-uniform) + block count
  unsigned long long* wp = bm + (long long)blockIdx.x * 16 + wv * 4;
  if (lane == 0) {
    *reinterpret_cast<ulonglong2*>(wp)     = make_ulonglong2(w[0], w[1]);
    *reinterpret_cast<ulonglong2*>(wp + 2) = make_ulonglong2(w[2], w[3]);
  }
  __shared__ int s_wsum[kTPB / 64];
  if (lane == 0)
    s_wsum[wv] = __popcll(w[0]) + __popcll(w[1]) + __popcll(w[2]) + __popcll(w[3]);
  __syncthreads();
  if (t == 0)
    blk_cnt[blockIdx.x] = s_wsum[0] + s_wsum[1] + s_wsum[2] + s_wsum[3];
}

// Pass 2: one block per batch, exclusive scan over 4096 block counts.
__global__ void __launch_bounds__(256)
scan_kernel(const int* __restrict__ blk_cnt, int* __restrict__ blk_off,
            float* __restrict__ counts_out) {
  const int b = blockIdx.x;
  const int* cnt = blk_cnt + b * kNBlkPerBatch;
  int* off = blk_off + b * kNBlkPerBatch;
  const int t = threadIdx.x;
  constexpr int kPer = kNBlkPerBatch / 256;  // 16
  const int base = t * kPer;

  int vals[kPer];
  int s = 0;
#pragma unroll
  for (int k = 0; k < kPer; ++k) { vals[k] = cnt[base + k]; s += vals[k]; }

  const int lane = t & 63, wv = t >> 6;
  int incl = s;
#pragma unroll
  for (int d = 1; d < 64; d <<= 1) {
    int u = __shfl_up(incl, d, 64);
    if (lane >= d) incl += u;
  }
  __shared__ int wsum[4];
  if (lane == 63) wsum[wv] = incl;
  __syncthreads();
  int wbase = 0;
  for (int i = 0; i < wv; ++i) wbase += wsum[i];

  int run = wbase + incl - s;
#pragma unroll
  for (int k = 0; k < kPer; ++k) { off[base + k] = run; run += vals[k]; }

  if (t == 255) counts_out[b] = (float)run;  // batch total (uncapped)
}

// Pass 3: ranks from bitmask, conf from center row only; skip capped blocks.
__global__ void __launch_bounds__(kTPB)
peak_write_kernel(const float* __restrict__ hm,
                  const unsigned long long* __restrict__ bm,
                  const int* __restrict__ blk_off,
                  float* __restrict__ out) {
  const int boff = blk_off[blockIdx.x];  // block-uniform -> s_load
  if (boff >= kMaxPeaks) return;         // whole block past the cap

  const int t = threadIdx.x, lane = t & 63, wv = t >> 6;
  int b, c, y, x0;
  decode(blockIdx.x, t, b, c, y, x0);

  const unsigned long long* wp = bm + (long long)blockIdx.x * 16 + wv * 4;
  const unsigned long long w0 = wp[0], w1 = wp[1], w2 = wp[2], w3 = wp[3];

  int f[4];
  f[0] = (int)((w0 >> lane) & 1); f[1] = (int)((w1 >> lane) & 1);
  f[2] = (int)((w2 >> lane) & 1); f[3] = (int)((w3 >> lane) & 1);
  const int cnt = f[0] + f[1] + f[2] + f[3];

  // lane-exclusive rank directly from ballot words (no shuffle scan)
  const unsigned long long pm = (lane == 0) ? 0ull : ((~0ull) >> (64 - lane));
  const int lexcl = __popcll(w0 & pm) + __popcll(w1 & pm) +
                    __popcll(w2 & pm) + __popcll(w3 & pm);

  // cross-wave base via LDS (wave counts are uniform per wave)
  __shared__ int s_wsum[kTPB / 64];
  if (lane == 0)
    s_wsum[wv] = __popcll(w0) + __popcll(w1) + __popcll(w2) + __popcll(w3);
  __syncthreads();
  int wbase = 0;
  for (int i = 0; i < wv; ++i) wbase += s_wsum[i];

  int rank = boff + wbase + lexcl;
  if (cnt == 0) return;

  // conf values: center row only
  const float* img = hm + (long long)b * kNPB + c * (kH * kW);
  const float4 cv = *reinterpret_cast<const float4*>(img + y * kW + x0);
  const float v[4] = {cv.x, cv.y, cv.z, cv.w};

  float* pb = out + (long long)b * kMaxPeaks * 3;
#pragma unroll
  for (int i = 0; i < 4; ++i) {
    if (f[i] && rank < kMaxPeaks) {
      float* o = pb + (long long)rank * 3;
      o[0] = (float)(x0 + i);
      o[1] = (float)y;
      o[2] = v[i];
    }
    rank += f[i];
  }
}

extern "C" void kernel_launch(void* const* d_in, const int* in_sizes, int n_in,
                              void* d_out, int out_size, void* d_ws, size_t ws_size,
                              hipStream_t stream) {
  const float* hm = (const float*)d_in[0];
  float* out = (float*)d_out;

  // ws layout: bitmasks 32768*16 u64 (4 MB) | blk_cnt 32768 int | blk_off 32768 int
  unsigned long long* bm = (unsigned long long*)d_ws;
  int* blk_cnt = (int*)(bm + (long long)kNBlocks * 16);
  int* blk_off = blk_cnt + kNBlocks;

  peak_count_kernel<<<kNBlocks, kTPB, 0, stream>>>(hm, bm, blk_cnt);
  scan_kernel<<<kB, 256, 0, stream>>>(blk_cnt, blk_off, out + kPeaksElems);
  peak_write_kernel<<<kNBlocks, kTPB, 0, stream>>>(hm, bm, blk_off, out);
}

// Round 4
// 220.056 us; speedup vs baseline: 13.6086x; 1.0634x over previous
//
#include <hip/hip_runtime.h>

// Three-pass peak detection + ordered compaction, (8,16,512,512) fp32.
// History: R2 single-pass decoupled lookback = 2.9ms (cross-XCD coherence
// latency — dead end). R3 (2-row blocks) = 234us total, kernels ~2.5 TB/s
// effective => latency-bound. R4: 4 chunks/block, 12 row-loads in flight per
// thread for MLP; pass3 reads bitmasks + int4 offsets, center rows only
// (L3-warm), skips chunks past the max_peaks cap (counts ~467K > 262144).

namespace {
constexpr int kB = 8;
constexpr int kC = 16;
constexpr int kH = 512;
constexpr int kW = 512;
constexpr int kNPB = kC * kH * kW;                  // 4,194,304 px / batch
constexpr int kMaxPeaks = 262144;
constexpr int kTPB = 256;
constexpr int kChunk = kTPB * 4;                    // 1024 px = 2 rows
constexpr int kChunksPerBlk = 4;
constexpr int kNChunksPerBatch = kNPB / kChunk;     // 4096
constexpr int kNChunks = kB * kNChunksPerBatch;     // 32768
constexpr int kNBlkStream = kNChunks / kChunksPerBlk;  // 8192
constexpr long long kPeaksElems = (long long)kB * kMaxPeaks * 3;
constexpr float kNeg = -3.402823466e38f;
}

__device__ __forceinline__ float fmax3(float a, float b, float c) {
  return fmaxf(fmaxf(a, b), c);  // -> v_max3_f32
}
__device__ __forceinline__ float4 neg4() {
  return make_float4(kNeg, kNeg, kNeg, kNeg);
}

// Pass 1: 4 chunks/block; all 12 row float4 loads issued before compute.
__global__ void __launch_bounds__(kTPB)
peak_count_kernel(const float* __restrict__ hm,
                  unsigned long long* __restrict__ bm,
                  int* __restrict__ cnts) {
  const int t = threadIdx.x, lane = t & 63, wv = t >> 6;
  const int chunk0 = blockIdx.x * kChunksPerBlk;
  __shared__ int s_wsum[kChunksPerBlk][kTPB / 64];

  const float* basep[kChunksPerBlk];
  int yv[kChunksPerBlk], xv[kChunksPerBlk];
  float4 r[kChunksPerBlk][3];
#pragma unroll
  for (int k = 0; k < kChunksPerBlk; ++k) {
    const int chunk = chunk0 + k;
    const int b = chunk >> 12;                       // 4096 chunks / batch
    const int local = (chunk & 4095) * kChunk + t * 4;
    const int c = local >> 18;
    const int y = (local >> 9) & (kH - 1);
    const int x0 = local & (kW - 1);                 // multiple of 4
    const float* p = hm + (long long)b * kNPB + c * (kH * kW) + y * kW + x0;
    basep[k] = p; yv[k] = y; xv[k] = x0;
    r[k][1] = *reinterpret_cast<const float4*>(p);
    r[k][0] = (y > 0)      ? *reinterpret_cast<const float4*>(p - kW) : neg4();
    r[k][2] = (y < kH - 1) ? *reinterpret_cast<const float4*>(p + kW) : neg4();
  }

#pragma unroll
  for (int k = 0; k < kChunksPerBlk; ++k) {
    const int y = yv[k], x0 = xv[k];
    const float* p = basep[k];
    float a[3][6];
#pragma unroll
    for (int j = 0; j < 3; ++j) {
      const float4 q = r[k][j];
      float L = __shfl_up(q.w, 1, 64);
      float R = __shfl_down(q.x, 1, 64);
      const bool ok = (j == 1) ? true : (j == 0 ? (y > 0) : (y < kH - 1));
      const float* rp = p + (j - 1) * kW;
      if (lane == 0)  L = (ok && x0 > 0)      ? rp[-1] : kNeg;  // L1-hit fixup
      if (lane == 63) R = (ok && x0 + 4 < kW) ? rp[4]  : kNeg;
      a[j][0] = L; a[j][1] = q.x; a[j][2] = q.y; a[j][3] = q.z; a[j][4] = q.w;
      a[j][5] = R;
    }
    float cm[6];
#pragma unroll
    for (int i = 0; i < 6; ++i) cm[i] = fmax3(a[0][i], a[1][i], a[2][i]);
    unsigned long long w[4];
    int csum = 0;
#pragma unroll
    for (int i = 0; i < 4; ++i) {
      const float v = a[1][i + 1];
      const float m = fmax3(cm[i], cm[i + 1], cm[i + 2]);
      w[i] = __ballot((v == m) && (v > 0.0f));
      csum += __popcll(w[i]);
    }
    if (lane == 0) {
      unsigned long long* wp = bm + (long long)(chunk0 + k) * 16 + wv * 4;
      *reinterpret_cast<ulonglong2*>(wp)     = make_ulonglong2(w[0], w[1]);
      *reinterpret_cast<ulonglong2*>(wp + 2) = make_ulonglong2(w[2], w[3]);
      s_wsum[k][wv] = csum;
    }
  }
  __syncthreads();
  if (t < kChunksPerBlk)
    cnts[chunk0 + t] =
        s_wsum[t][0] + s_wsum[t][1] + s_wsum[t][2] + s_wsum[t][3];
}

// Pass 2: one block per batch, exclusive scan over 4096 chunk counts.
__global__ void __launch_bounds__(256)
scan_kernel(const int* __restrict__ cnts, int* __restrict__ offs,
            float* __restrict__ counts_out) {
  const int b = blockIdx.x;
  const int* cnt = cnts + b * kNChunksPerBatch;
  int* off = offs + b * kNChunksPerBatch;
  const int t = threadIdx.x;
  constexpr int kPer = kNChunksPerBatch / 256;  // 16
  const int base = t * kPer;

  int vals[kPer];
  int s = 0;
#pragma unroll
  for (int k = 0; k < kPer; ++k) { vals[k] = cnt[base + k]; s += vals[k]; }

  const int lane = t & 63, wv = t >> 6;
  int incl = s;
#pragma unroll
  for (int d = 1; d < 64; d <<= 1) {
    int u = __shfl_up(incl, d, 64);
    if (lane >= d) incl += u;
  }
  __shared__ int wsum[4];
  if (lane == 63) wsum[wv] = incl;
  __syncthreads();
  int wbase = 0;
  for (int i = 0; i < wv; ++i) wbase += wsum[i];

  int run = wbase + incl - s;
#pragma unroll
  for (int k = 0; k < kPer; ++k) { off[base + k] = run; run += vals[k]; }

  if (t == 255) counts_out[b] = (float)run;  // batch total (uncapped)
}

// Pass 3: 4 chunks/block; ranks from bitmasks, conf from center rows only.
__global__ void __launch_bounds__(kTPB)
peak_write_kernel(const float* __restrict__ hm,
                  const unsigned long long* __restrict__ bm,
                  const int* __restrict__ offs,
                  float* __restrict__ out) {
  const int t = threadIdx.x, lane = t & 63, wv = t >> 6;
  const int chunk0 = blockIdx.x * kChunksPerBlk;
  const int4 off4 = *reinterpret_cast<const int4*>(offs + chunk0);
  const int boff[kChunksPerBlk] = {off4.x, off4.y, off4.z, off4.w};
  __shared__ int s_wsum[kChunksPerBlk][kTPB / 64];

  unsigned long long w[kChunksPerBlk][4];
  int lexcl[kChunksPerBlk];
  const unsigned long long pm = (lane == 0) ? 0ull : ((~0ull) >> (64 - lane));
#pragma unroll
  for (int k = 0; k < kChunksPerBlk; ++k) {
    if (boff[k] >= kMaxPeaks) continue;  // block-uniform skip
    const unsigned long long* wp = bm + (long long)(chunk0 + k) * 16 + wv * 4;
    const ulonglong2 w01 = *reinterpret_cast<const ulonglong2*>(wp);
    const ulonglong2 w23 = *reinterpret_cast<const ulonglong2*>(wp + 2);
    w[k][0] = w01.x; w[k][1] = w01.y; w[k][2] = w23.x; w[k][3] = w23.y;
    lexcl[k] = __popcll(w[k][0] & pm) + __popcll(w[k][1] & pm) +
               __popcll(w[k][2] & pm) + __popcll(w[k][3] & pm);
    if (lane == 0)
      s_wsum[k][wv] = __popcll(w[k][0]) + __popcll(w[k][1]) +
                      __popcll(w[k][2]) + __popcll(w[k][3]);
  }
  __syncthreads();
#pragma unroll
  for (int k = 0; k < kChunksPerBlk; ++k) {
    if (boff[k] >= kMaxPeaks) continue;
    int f[4];
    f[0] = (int)((w[k][0] >> lane) & 1); f[1] = (int)((w[k][1] >> lane) & 1);
    f[2] = (int)((w[k][2] >> lane) & 1); f[3] = (int)((w[k][3] >> lane) & 1);
    const int cnt = f[0] + f[1] + f[2] + f[3];
    int wbase = 0;
    for (int i = 0; i < wv; ++i) wbase += s_wsum[k][i];
    int rank = boff[k] + wbase + lexcl[k];
    if (cnt == 0) continue;

    const int chunk = chunk0 + k;
    const int b = chunk >> 12;
    const int local = (chunk & 4095) * kChunk + t * 4;
    const int c = local >> 18;
    const int y = (local >> 9) & (kH - 1);
    const int x0 = local & (kW - 1);
    const float4 cv = *reinterpret_cast<const float4*>(
        hm + (long long)b * kNPB + c * (kH * kW) + y * kW + x0);
    const float v[4] = {cv.x, cv.y, cv.z, cv.w};

    float* pb = out + (long long)b * kMaxPeaks * 3;
#pragma unroll
    for (int i = 0; i < 4; ++i) {
      if (f[i] && rank < kMaxPeaks) {
        float* o = pb + (long long)rank * 3;
        o[0] = (float)(x0 + i);
        o[1] = (float)y;
        o[2] = v[i];
      }
      rank += f[i];
    }
  }
}

extern "C" void kernel_launch(void* const* d_in, const int* in_sizes, int n_in,
                              void* d_out, int out_size, void* d_ws, size_t ws_size,
                              hipStream_t stream) {
  const float* hm = (const float*)d_in[0];
  float* out = (float*)d_out;

  // ws: bitmasks 32768*16 u64 (4 MB) | chunk counts 32768 int | offsets 32768 int
  unsigned long long* bm = (unsigned long long*)d_ws;
  int* cnts = (int*)(bm + (long long)kNChunks * 16);
  int* offs = cnts + kNChunks;

  peak_count_kernel<<<kNBlkStream, kTPB, 0, stream>>>(hm, bm, cnts);
  scan_kernel<<<kB, 256, 0, stream>>>(cnts, offs, out + kPeaksElems);
  peak_write_kernel<<<kNBlkStream, kTPB, 0, stream>>>(hm, bm, offs, out);
}

// Round 6
// 219.961 us; speedup vs baseline: 13.6145x; 1.0004x over previous
//
#include <hip/hip_runtime.h>

// Three-pass peak detection + ordered compaction, (8,16,512,512) fp32.
// History: R2 single-pass decoupled lookback = 2.9ms (cross-XCD coherence —
// dead end). R4 (chunked, fixup loads inside compute loop) = 220us total,
// ~126us ours vs ~94us fixed harness floor. R5: row-per-wave strips — zero
// edge-fixup loads, 1.25x row loads (vs 3x), ballot flags, no barriers.
// (R5 fix: __builtin_amdgcn_writelane doesn't exist on gfx950/ROCm — capture
// the wave-uniform ballot word with a predicated select instead.)

namespace {
constexpr int kB = 8;
constexpr int kC = 16;
constexpr int kH = 512;
constexpr int kW = 512;
constexpr int kNPB = kC * kH * kW;              // 4,194,304 px / batch
constexpr int kMaxPeaks = 262144;
constexpr int kRows = 8;                        // rows per strip
constexpr int kStripsPerImg = kH / kRows;       // 64
constexpr int kStripsPerBatch = kC * kStripsPerImg;  // 1024
constexpr int kNStrips = kB * kStripsPerBatch;  // 8192
constexpr int kWPB = 4;                         // waves (strips) per block
constexpr int kTPB = 64 * kWPB;                 // 256
constexpr long long kPeaksElems = (long long)kB * kMaxPeaks * 3;
constexpr float kNeg = -3.402823466e38f;
}

__device__ __forceinline__ float fmax3(float a, float b, float c) {
  return fmaxf(fmaxf(a, b), c);  // -> v_max3_f32
}

// Pass 1: wave = one 8-row strip of one channel image; lane l owns x=l*8..+7.
// Emits 64 x u64 ballot-mask words per strip (word r*8+j: bit l = flag of px
// (row y0+r, x=l*8+j)) + strip peak count.
__global__ void __launch_bounds__(kTPB)
peak_count_kernel(const float* __restrict__ hm,
                  unsigned long long* __restrict__ bmw,
                  int* __restrict__ cnts) {
  const int t = threadIdx.x, lane = t & 63, wv = t >> 6;
  const int s = blockIdx.x * kWPB + wv;
  const int b = s >> 10;                 // 1024 strips / batch
  const int si = s & 1023;
  const int c = si >> 6;                 // 64 strips / image
  const int y0 = (si & 63) * kRows;
  const float* rp = hm + (long long)b * kNPB + c * (kH * kW) + y0 * kW + lane * 8;

  // Load rows y0-1 .. y0+8 (10 rows x 8 px) up front. Image-edge rows -> -inf.
  float a[10][8];
#pragma unroll
  for (int i = 1; i <= 8; ++i) {
    const float4 q0 = *reinterpret_cast<const float4*>(rp + (i - 1) * kW);
    const float4 q1 = *reinterpret_cast<const float4*>(rp + (i - 1) * kW + 4);
    a[i][0] = q0.x; a[i][1] = q0.y; a[i][2] = q0.z; a[i][3] = q0.w;
    a[i][4] = q1.x; a[i][5] = q1.y; a[i][6] = q1.z; a[i][7] = q1.w;
  }
  if (y0 > 0) {
    const float4 q0 = *reinterpret_cast<const float4*>(rp - kW);
    const float4 q1 = *reinterpret_cast<const float4*>(rp - kW + 4);
    a[0][0] = q0.x; a[0][1] = q0.y; a[0][2] = q0.z; a[0][3] = q0.w;
    a[0][4] = q1.x; a[0][5] = q1.y; a[0][6] = q1.z; a[0][7] = q1.w;
  } else {
#pragma unroll
    for (int j = 0; j < 8; ++j) a[0][j] = kNeg;
  }
  if (y0 + kRows < kH) {
    const float4 q0 = *reinterpret_cast<const float4*>(rp + 8 * kW);
    const float4 q1 = *reinterpret_cast<const float4*>(rp + 8 * kW + 4);
    a[9][0] = q0.x; a[9][1] = q0.y; a[9][2] = q0.z; a[9][3] = q0.w;
    a[9][4] = q1.x; a[9][5] = q1.y; a[9][6] = q1.z; a[9][7] = q1.w;
  } else {
#pragma unroll
    for (int j = 0; j < 8; ++j) a[9][j] = kNeg;
  }

  unsigned long long myword = 0;  // lane (r*8+j) keeps ballot word (r,j)
  int scnt = 0;                   // wave-uniform strip count
#pragma unroll
  for (int r = 0; r < kRows; ++r) {
    float cm[8];
#pragma unroll
    for (int j = 0; j < 8; ++j) cm[j] = fmax3(a[r][j], a[r + 1][j], a[r + 2][j]);
    float hl = __shfl_up(cm[7], 1, 64);
    float hr = __shfl_down(cm[0], 1, 64);
    if (lane == 0) hl = kNeg;    // x = -1 (image edge)
    if (lane == 63) hr = kNeg;   // x = 512 (image edge)
    float m[8];
    m[0] = fmax3(hl, cm[0], cm[1]);
#pragma unroll
    for (int j = 1; j < 7; ++j) m[j] = fmax3(cm[j - 1], cm[j], cm[j + 1]);
    m[7] = fmax3(cm[6], cm[7], hr);
#pragma unroll
    for (int j = 0; j < 8; ++j) {
      const float v = a[r + 1][j];
      const unsigned long long wj = __ballot((v == m[j]) && (v > 0.0f));
      scnt += (int)__popcll(wj);
      if (lane == r * 8 + j) myword = wj;  // wave-uniform value, 1-lane capture
    }
  }
  bmw[(long long)s * 64 + lane] = myword;
  if (lane == 0) cnts[s] = scnt;
}

// Pass 2: one block per batch, exclusive scan over 1024 strip counts.
__global__ void __launch_bounds__(256)
scan_kernel(const int* __restrict__ cnts, int* __restrict__ offs,
            float* __restrict__ counts_out) {
  const int b = blockIdx.x;
  const int* cnt = cnts + b * kStripsPerBatch;
  int* off = offs + b * kStripsPerBatch;
  const int t = threadIdx.x;
  constexpr int kPer = kStripsPerBatch / 256;  // 4
  const int base = t * kPer;

  int vals[kPer];
  int ssum = 0;
#pragma unroll
  for (int k = 0; k < kPer; ++k) { vals[k] = cnt[base + k]; ssum += vals[k]; }

  const int lane = t & 63, wv = t >> 6;
  int incl = ssum;
#pragma unroll
  for (int d = 1; d < 64; d <<= 1) {
    int u = __shfl_up(incl, d, 64);
    if (lane >= d) incl += u;
  }
  __shared__ int wsum[4];
  if (lane == 63) wsum[wv] = incl;
  __syncthreads();
  int wbase = 0;
  for (int i = 0; i < wv; ++i) wbase += wsum[i];

  int run = wbase + incl - ssum;
#pragma unroll
  for (int k = 0; k < kPer; ++k) { off[base + k] = run; run += vals[k]; }

  if (t == 255) counts_out[b] = (float)run;  // batch total (uncapped)
}

// Pass 3: wave = one strip; ranks from mask popcounts (LDS broadcast, no
// shuffles, no barriers); conf from center rows only; cap-skip whole strips.
__global__ void __launch_bounds__(kTPB)
peak_write_kernel(const float* __restrict__ hm,
                  const unsigned long long* __restrict__ bmw,
                  const int* __restrict__ offs,
                  float* __restrict__ out) {
  __shared__ unsigned long long s_w[kWPB][64];
  const int t = threadIdx.x, lane = t & 63, wv = t >> 6;
  const int s = blockIdx.x * kWPB + wv;
  const int off0 = offs[s];
  if (off0 >= kMaxPeaks) return;  // wave-uniform; kernel has no barriers
  const int b = s >> 10, si = s & 1023, c = si >> 6, y0 = (si & 63) * kRows;
  const float* rp = hm + (long long)b * kNPB + c * (kH * kW) + y0 * kW + lane * 8;

  // conf values (8 rows x 8 px), issued up front
  float4 cv[kRows][2];
#pragma unroll
  for (int r = 0; r < kRows; ++r) {
    cv[r][0] = *reinterpret_cast<const float4*>(rp + r * kW);
    cv[r][1] = *reinterpret_cast<const float4*>(rp + r * kW + 4);
  }

  // mask words -> per-wave LDS region; same-wave produce/consume (lgkmcnt only)
  s_w[wv][lane] = bmw[(long long)s * 64 + lane];

  const unsigned long long pm = (lane == 0) ? 0ull : (~0ull >> (64 - lane));
  int base = off0;
  float* pb = out + (long long)b * kMaxPeaks * 3;
#pragma unroll
  for (int r = 0; r < kRows; ++r) {
    unsigned long long w[8];
#pragma unroll
    for (int j = 0; j < 8; ++j) w[j] = s_w[wv][r * 8 + j];
    int lexcl = 0, rowcnt = 0;
#pragma unroll
    for (int j = 0; j < 8; ++j) {
      lexcl += (int)__popcll(w[j] & pm);
      rowcnt += (int)__popcll(w[j]);
    }
    int rank = base + lexcl;
    const float vv[8] = {cv[r][0].x, cv[r][0].y, cv[r][0].z, cv[r][0].w,
                         cv[r][1].x, cv[r][1].y, cv[r][1].z, cv[r][1].w};
    const float fy = (float)(y0 + r);
#pragma unroll
    for (int j = 0; j < 8; ++j) {
      const int f = (int)((w[j] >> lane) & 1);
      if (f && rank < kMaxPeaks) {
        float* o = pb + (long long)rank * 3;
        o[0] = (float)(lane * 8 + j);
        o[1] = fy;
        o[2] = vv[j];
      }
      rank += f;
    }
    base += rowcnt;
    if (base >= kMaxPeaks) break;  // uniform: all later rows past the cap
  }
}

extern "C" void kernel_launch(void* const* d_in, const int* in_sizes, int n_in,
                              void* d_out, int out_size, void* d_ws, size_t ws_size,
                              hipStream_t stream) {
  const float* hm = (const float*)d_in[0];
  float* out = (float*)d_out;

  // ws: masks 8192*64 u64 (4 MB) | strip counts 8192 int | offsets 8192 int
  unsigned long long* bmw = (unsigned long long*)d_ws;
  int* cnts = (int*)(bmw + (long long)kNStrips * 64);
  int* offs = cnts + kNStrips;

  peak_count_kernel<<<kNStrips / kWPB, kTPB, 0, stream>>>(hm, bmw, cnts);
  scan_kernel<<<kB, 256, 0, stream>>>(cnts, offs, out + kPeaksElems);
  peak_write_kernel<<<kNStrips / kWPB, kTPB, 0, stream>>>(hm, bmw, offs, out);
}